// Round 5
// baseline (235.152 us; speedup 1.0000x reference)
//
#include <hip/hip_runtime.h>

// EMA over time: y_t = 0.1*y_{t-1} + 0.9*x_t, x: [B=16, T=4000, C=512] fp32.
//
// R8: persistent column-segments. R7 proved the wall is DRAM/fabric access-
// pattern efficiency (chunk-major+XCD swizzle gave the first win, 83->~76us;
// MLP depth / occupancy / store phasing / nt-stores all null). This round
// takes the ordering theory to its limit:
//   - Each thread owns one (b,c4) column for V=125 CONSECUTIVE timesteps,
//     carrying EMA state in registers: read amp 1.5x -> 1.064x (warmup W=8
//     paid once per 125 outputs).
//   - Grid = 512 blocks x 128 threads = exactly 2 blocks/CU: perfect
//     balance; each CU walks 2 contiguous 250KB input slabs linearly and
//     writes 2 contiguous slabs — the same address structure as the
//     6.6 TB/s fill kernel. XCD-chunked bijective swizzle (512%8==0) keeps
//     each XCD inside its own 2-batch 16MB region.
//   - Ping-pong 2x5-row double buffer, all indices compile-time (rule #20),
//     ~10 loads in flight per thread: 8 waves/CU x ~5KB ≈ 40KB in flight
//     vs ~9KB needed for 6.3TB/s @375ns. Occupancy 12.5% is fine (R6: 28
//     vs 43% occ = identical time).
// Truncated warmup: 0.1^8 ~ 1e-8 (threshold 7.8e-3), as all prior rounds.

constexpr int B_   = 16;
constexpr int T_   = 4000;
constexpr int C_   = 512;
constexpr int NC4_ = C_ / 4;      // 128 float4 columns per row
constexpr int V_   = 125;         // timesteps per thread (sequential span)
constexpr int NSEG_ = T_ / V_;    // 32 segments per batch
constexpr int W_   = 8;           // lookback warmup (0.1^8 ~ 1e-8)
constexpr int PH_  = 5;           // rows per phase (125 = 25 phases)
constexpr int NPH_ = V_ / PH_;    // 25
constexpr int NXCD_ = 8;
constexpr int NWG_  = B_ * NSEG_; // 512 blocks (128 threads each)
constexpr int CPX_  = NWG_ / NXCD_; // 64

__global__ __launch_bounds__(128, 2) void ema_seg_scan(const float* __restrict__ x,
                                                       float* __restrict__ y) {
    // Bijective XCD-chunked swizzle: XCD x owns units [64x, 64x+64) -> b in
    // {2x, 2x+1}, segments walked in order within each b.
    int swz = (blockIdx.x & (NXCD_ - 1)) * CPX_ + blockIdx.x / NXCD_;
    int c4  = threadIdx.x;            // 0..127, lane-major -> coalesced
    int b   = swz >> 5;               // / NSEG_   (wave-uniform)
    int seg = swz & (NSEG_ - 1);      //           (wave-uniform)
    int t0  = seg * V_;

    const float4* base = (const float4*)(x + (size_t)b * T_ * C_) + c4;
    float4*       q    = (float4*)(y + ((size_t)b * T_ + t0) * C_) + c4;

    const float a = 0.9f, om = 0.1f;
    auto fma4 = [&](float4& acc, const float4& v) {
        acc.x = om * acc.x + a * v.x;
        acc.y = om * acc.y + a * v.y;
        acc.z = om * acc.z + a * v.z;
        acc.w = om * acc.w + a * v.w;
    };

    float4 acc = make_float4(0.f, 0.f, 0.f, 0.f);

    // ---- warmup: 8 rows before t0 (zeroed for seg 0) ----
    {
        int tw = (seg > 0) ? (t0 - W_) : 0;
        float4 w[W_];
        #pragma unroll
        for (int i = 0; i < W_; ++i) w[i] = base[(size_t)(tw + i) * NC4_];
        #pragma unroll
        for (int i = 0; i < W_; ++i) fma4(acc, w[i]);
        float sel = (seg > 0) ? 1.f : 0.f;
        acc.x *= sel; acc.y *= sel; acc.z *= sel; acc.w *= sel;
    }

    // ---- main scan: 25 phases of 5 rows, ping-pong prefetch ----
    float4 bufA[PH_], bufB[PH_];
    #pragma unroll
    for (int i = 0; i < PH_; ++i) bufA[i] = base[(size_t)(t0 + i) * NC4_];

    #pragma unroll
    for (int p = 0; p < (NPH_ - 1) / 2; ++p) {          // 12 double-phases
        const int rA = (2 * p) * PH_;
        const int rB = (2 * p + 1) * PH_;
        const int rC = (2 * p + 2) * PH_;
        #pragma unroll
        for (int i = 0; i < PH_; ++i) bufB[i] = base[(size_t)(t0 + rB + i) * NC4_];
        #pragma unroll
        for (int i = 0; i < PH_; ++i) { fma4(acc, bufA[i]); q[(size_t)(rA + i) * NC4_] = acc; }
        #pragma unroll
        for (int i = 0; i < PH_; ++i) bufA[i] = base[(size_t)(t0 + rC + i) * NC4_];
        #pragma unroll
        for (int i = 0; i < PH_; ++i) { fma4(acc, bufB[i]); q[(size_t)(rB + i) * NC4_] = acc; }
    }
    // final phase: rows 120..124 (already in bufA)
    #pragma unroll
    for (int i = 0; i < PH_; ++i) {
        fma4(acc, bufA[i]);
        q[(size_t)(V_ - PH_ + i) * NC4_] = acc;
    }
}

extern "C" void kernel_launch(void* const* d_in, const int* in_sizes, int n_in,
                              void* d_out, int out_size, void* d_ws, size_t ws_size,
                              hipStream_t stream) {
    const float* x = (const float*)d_in[0];
    float* y = (float*)d_out;
    ema_seg_scan<<<NWG_, 128, 0, stream>>>(x, y);
}

// Round 6
// 230.540 us; speedup vs baseline: 1.0200x; 1.0200x over previous
//
#include <hip/hip_runtime.h>

// EMA over time: y_t = 0.1*y_{t-1} + 0.9*x_t, x: [B=16, T=4000, C=512] fp32.
// Chunked-scan with truncated warmup: 0.1^8 ~ 1e-8 (threshold 7.8e-3).
//
// R9: R7's ordering (the only proven win: chunk-major + XCD swizzle) plus
// ONE new variable: a REAL 24-deep per-wave load batch. Every prior attempt
// at load batching (R3/R5/R6/R8) was silently sunk by the compiler
// (VGPR_Count 32/36/40/32 proves the batch never existed; sched_barrier(0)
// is scheduler-only and MachineSink ignores it). This round pins the batch
// with asm volatile("" ::: "memory") — an IR-level memory clobber: no pass
// may sink a load below it or re-load above it, so all 24 loads ISSUE
// before the fence while s_waitcnt's still trickle in lazily at each use.
// __launch_bounds__(256,3) (<=170 VGPR) guarantees the ~120-VGPR live set
// doesn't spill; 12 waves/CU x 24KB issued ≈ 290KB/CU in flight vs the
// ~40KB Little's-law requirement at ~700ns loaded latency.
// Verification gate: VGPR_Count must jump to ~100-130, else round is void.

typedef float f32x4 __attribute__((ext_vector_type(4)));

constexpr int B_ = 16;
constexpr int T_ = 4000;
constexpr int C_ = 512;
constexpr int L_ = 16;            // output timesteps per thread
constexpr int W_ = 8;             // lookback warmup (0.1^8 ~ 1e-8)
constexpr int NC4_ = C_ / 4;      // 128 float4 columns per row
constexpr int NCHUNK_ = T_ / L_;  // 250
constexpr int NXCD_ = 8;
constexpr int NWG_ = B_ * NC4_ * NCHUNK_ / 256;  // 2000
constexpr int CPX_ = NWG_ / NXCD_;               // 250

__global__ __launch_bounds__(256, 3) void ema_chunk_scan(const float* __restrict__ x,
                                                         float* __restrict__ y) {
    // Bijective XCD-chunked block swizzle (2000 % 8 == 0): XCD i owns
    // b in {2i, 2i+1}, chunks walked sequentially within each b.
    int swz = (blockIdx.x % NXCD_) * CPX_ + blockIdx.x / NXCD_;

    int half = threadIdx.x >> 7;          // 0/1: two chunks per block
    int c4   = threadIdx.x & (NC4_ - 1);  // lane-major -> coalesced
    int b     = swz / 125;                // wave-uniform
    int chunk = (swz % 125) * 2 + half;   // wave-uniform

    int t0 = chunk * L_;
    int tw = (chunk > 0) ? (t0 - W_) : 0;

    const f32x4* base = (const f32x4*)(x + (size_t)b * T_ * C_) + c4;
    f32x4*       q    = (f32x4*)(y + ((size_t)b * T_ + t0) * C_) + c4;

    // ---- issue ALL 24 loads; the memory clobber pins issue order ----
    f32x4 w[W_];
    #pragma unroll
    for (int i = 0; i < W_; ++i) w[i] = base[(size_t)(tw + i) * NC4_];
    f32x4 m[L_];
    #pragma unroll
    for (int i = 0; i < L_; ++i) m[i] = base[(size_t)(t0 + i) * NC4_];
    asm volatile("" ::: "memory");   // no load may sink below; no reload above

    const float a = 0.9f, om = 0.1f;
    f32x4 acc = (f32x4)0.f;

    // Warmup chain (no stores); waits on w[] trickle in here while m[]
    // loads remain outstanding.
    #pragma unroll
    for (int i = 0; i < W_; ++i) acc = om * acc + a * w[i];

    // chunk 0: no history — zero the warmup state (wave-uniform select).
    float sel = (chunk > 0) ? 1.f : 0.f;
    acc *= sel;

    // Main chain: store each result as produced (stores fire-and-forget).
    #pragma unroll
    for (int i = 0; i < L_; ++i) {
        acc = om * acc + a * m[i];
        q[(size_t)i * NC4_] = acc;
    }
}

extern "C" void kernel_launch(void* const* d_in, const int* in_sizes, int n_in,
                              void* d_out, int out_size, void* d_ws, size_t ws_size,
                              hipStream_t stream) {
    const float* x = (const float*)d_in[0];
    float* y = (float*)d_out;
    ema_chunk_scan<<<NWG_, 256, 0, stream>>>(x, y);
}